// Round 1
// baseline (1596.537 us; speedup 1.0000x reference)
//
#include <hip/hip_runtime.h>

// ---------------------------------------------------------------------------
// GCN, 6 layers, N=1M nodes, E=16M edges.
// R6: layer kernels were latency-bound (VALUBusy 1.1%, HBM 21%, occupancy
// 44.6% = grid-capped at 245 blocks / 256 CUs, ~4 gathers in flight/wave ->
// Little's law gives ~615cy avg gather latency at 64 loads in flight/CU).
// Fix: (a) BSHIFT 12->11: 489 dst buckets of 2048 nodes, 24KB LDS -> 2
// blocks/CU (8 waves/SIMD); (b) 8-edge unroll: issue 8 float4 gathers before
// any LDS atomic -> 8 in flight/wave. ~4x MLP total.
// Edges ordered by (dst_bucket, src_superblock[4 of 256K nodes]); packed
// edge = (src<<11)|(dst&2047). Build-phase hist arrays alias sA (dead after
// scatter) to keep workspace <= 103 MB.
// ---------------------------------------------------------------------------

#define BT 256            // build-kernel block size
#define NBLK 256          // partition blocks
#define BSHIFT 11         // 2048 nodes per dst bucket
#define BSIZE 2048
#define LMASK 2047
#define SSH 18            // src super-block shift (256K nodes = 4MB float4 window)
#define NBINS 2048        // (dst_bucket<<2)|src_sb, padded (real: 489*4=1956)
#define M (NBLK * NBINS)  // 524288
#define BTL 1024          // layer-kernel block size

__device__ __forceinline__ int edge_key(int s, int d) {
  return ((d >> BSHIFT) << 2) | (s >> SSH);
}

// s0 = feat * norm
__global__ void k_init(const float* __restrict__ feat, const float* __restrict__ norm,
                       float* __restrict__ s0, int N) {
  int i = blockIdx.x * BT + threadIdx.x;
  if (i < N) s0[i] = feat[i] * norm[i];
}

// P1: per-block LDS histogram of (dst_bucket, src_sb) bins
__global__ void k_phist(const int* __restrict__ src, const int* __restrict__ dst,
                        int* __restrict__ histB, int E, int chunk) {
  __shared__ int h[NBINS];
  for (int i = threadIdx.x; i < NBINS; i += BT) h[i] = 0;
  __syncthreads();
  int b = blockIdx.x;
  int beg = b * chunk, end = min(beg + chunk, E);
  int i = beg + (int)threadIdx.x * 4;  // beg is 16B-aligned (chunk % 4 == 0)
  for (; i + 3 < end; i += BT * 4) {
    int4 u = *(const int4*)(src + i);
    int4 v = *(const int4*)(dst + i);
    atomicAdd(&h[edge_key(u.x, v.x)], 1);
    atomicAdd(&h[edge_key(u.y, v.y)], 1);
    atomicAdd(&h[edge_key(u.z, v.z)], 1);
    atomicAdd(&h[edge_key(u.w, v.w)], 1);
  }
  for (; i < end; ++i) atomicAdd(&h[edge_key(src[i], dst[i])], 1);
  __syncthreads();
  for (int k = threadIdx.x; k < NBINS; k += BT) histB[b * NBINS + k] = h[k];
}

// Tiled transpose: in[R][C] -> out[C][R]. R,C multiples of 64. grid(C/64,R/64)
__global__ void k_transp(const int* __restrict__ in, int* __restrict__ out, int R, int C) {
  __shared__ int tile[64][65];
  int c0 = blockIdx.x * 64, r0 = blockIdx.y * 64;
  int tx = threadIdx.x & 63, ty = threadIdx.x >> 6;  // 64 x 4
  for (int j = 0; j < 16; ++j) {
    int r = ty + j * 4;
    tile[r][tx] = in[(r0 + r) * C + c0 + tx];
  }
  __syncthreads();
  for (int j = 0; j < 16; ++j) {
    int r = ty + j * 4;
    out[(c0 + r) * R + r0 + tx] = tile[tx][r];
  }
}

// scan A: per-block sums
__global__ void k_blockSum(const int* __restrict__ data, int* __restrict__ partial, int Mlen) {
  __shared__ int tmp[BT];
  int i = blockIdx.x * BT + threadIdx.x;
  tmp[threadIdx.x] = (i < Mlen) ? data[i] : 0;
  __syncthreads();
  for (int off = BT / 2; off > 0; off >>= 1) {
    if (threadIdx.x < off) tmp[threadIdx.x] += tmp[threadIdx.x + off];
    __syncthreads();
  }
  if (threadIdx.x == 0) partial[blockIdx.x] = tmp[0];
}

// scan B: exclusive scan of partials in place (single block)
__global__ void k_scanPartials(int* __restrict__ partial, int nb) {
  __shared__ int tmp[BT];
  __shared__ int carry;
  int t = threadIdx.x;
  if (t == 0) carry = 0;
  __syncthreads();
  for (int base = 0; base < nb; base += BT) {
    int i = base + t;
    int v = (i < nb) ? partial[i] : 0;
    tmp[t] = v;
    __syncthreads();
    for (int off = 1; off < BT; off <<= 1) {
      int x = 0;
      if (t >= off) x = tmp[t - off];
      __syncthreads();
      tmp[t] += x;
      __syncthreads();
    }
    if (i < nb) partial[i] = tmp[t] - v + carry;
    __syncthreads();
    if (t == BT - 1) carry += tmp[BT - 1];
    __syncthreads();
  }
}

// scan C: final exclusive scan in place
__global__ void k_scanFinal(int* __restrict__ data, const int* __restrict__ partial, int Mlen) {
  __shared__ int tmp[BT];
  int t = threadIdx.x;
  int i = blockIdx.x * BT + t;
  int v = (i < Mlen) ? data[i] : 0;
  tmp[t] = v;
  __syncthreads();
  for (int off = 1; off < BT; off <<= 1) {
    int x = 0;
    if (t >= off) x = tmp[t - off];
    __syncthreads();
    tmp[t] += x;
    __syncthreads();
  }
  if (i < Mlen) data[i] = tmp[t] - v + partial[blockIdx.x];
}

// P2: scatter packed edges with per-block LDS cursors
__global__ void k_pscatter(const int* __restrict__ src, const int* __restrict__ dst,
                           const int* __restrict__ scanT, unsigned int* __restrict__ packed,
                           int E, int chunk) {
  __shared__ int cur[NBINS];
  int b = blockIdx.x;
  for (int k = threadIdx.x; k < NBINS; k += BT) cur[k] = scanT[b * NBINS + k];
  __syncthreads();
  int beg = b * chunk, end = min(beg + chunk, E);
  int i = beg + (int)threadIdx.x * 4;
  for (; i + 3 < end; i += BT * 4) {
    int4 u = *(const int4*)(src + i);
    int4 v = *(const int4*)(dst + i);
    int p;
    p = atomicAdd(&cur[edge_key(u.x, v.x)], 1);
    packed[p] = ((unsigned)u.x << BSHIFT) | (unsigned)(v.x & LMASK);
    p = atomicAdd(&cur[edge_key(u.y, v.y)], 1);
    packed[p] = ((unsigned)u.y << BSHIFT) | (unsigned)(v.y & LMASK);
    p = atomicAdd(&cur[edge_key(u.z, v.z)], 1);
    packed[p] = ((unsigned)u.z << BSHIFT) | (unsigned)(v.z & LMASK);
    p = atomicAdd(&cur[edge_key(u.w, v.w)], 1);
    packed[p] = ((unsigned)u.w << BSHIFT) | (unsigned)(v.w & LMASK);
  }
  for (; i < end; ++i) {
    int p = atomicAdd(&cur[edge_key(src[i], dst[i])], 1);
    packed[p] = ((unsigned)src[i] << BSHIFT) | (unsigned)(dst[i] & LMASK);
  }
}

// --- layer kernels: one block per dst bucket ---
// bucket k edge range = [scanT[4k], scanT[4k+4])  (row 0 of scanT = bin starts)

#define ACC3(p)                                             \
  {                                                         \
    unsigned pp = (p);                                      \
    float4 m = ((const float4*)sPrev)[pp >> BSHIFT];        \
    int loc = pp & LMASK;                                   \
    atomicAdd(&a0[loc], m.x);                               \
    atomicAdd(&a1[loc], m.y);                               \
    atomicAdd(&a2[loc], m.z);                               \
  }

#define ACC1(p)                                             \
  {                                                         \
    unsigned pp = (p);                                      \
    atomicAdd(&a[pp & LMASK], sIn[pp >> BSHIFT]);           \
  }

// 8-wide main loop: issue all 8 gathers before any LDS atomic (MLP=8/wave)
#define GATH4(m, p) float4 m = ((const float4*)sPrev)[(p) >> BSHIFT];
#define ATOM3(m, p)                                         \
  {                                                         \
    int loc = (int)((p) & LMASK);                           \
    atomicAdd(&a0[loc], m.x);                               \
    atomicAdd(&a1[loc], m.y);                               \
    atomicAdd(&a2[loc], m.z);                               \
  }
#define GATH1(m, p) float m = sIn[(p) >> BSHIFT];
#define ATOM1(m, p) atomicAdd(&a[(p) & LMASK], m);

#define EDGE_LOOP3                                          \
  int abeg = min(end, (beg + 3) & ~3);                      \
  int t = beg + (int)threadIdx.x;                           \
  if (t < abeg) ACC3(packed[t]);                            \
  int i = abeg + (int)threadIdx.x * 8;                      \
  for (; i + 7 < end; i += BTL * 8) {                       \
    uint4 pa = *(const uint4*)(packed + i);                 \
    uint4 pb = *(const uint4*)(packed + i + 4);             \
    GATH4(m0, pa.x) GATH4(m1, pa.y)                         \
    GATH4(m2, pa.z) GATH4(m3, pa.w)                         \
    GATH4(m4, pb.x) GATH4(m5, pb.y)                         \
    GATH4(m6, pb.z) GATH4(m7, pb.w)                         \
    ATOM3(m0, pa.x) ATOM3(m1, pa.y)                         \
    ATOM3(m2, pa.z) ATOM3(m3, pa.w)                         \
    ATOM3(m4, pb.x) ATOM3(m5, pb.y)                         \
    ATOM3(m6, pb.z) ATOM3(m7, pb.w)                         \
  }                                                         \
  for (; i < end; ++i) ACC3(packed[i]);

#define EDGE_LOOP1                                          \
  int abeg = min(end, (beg + 3) & ~3);                      \
  int t = beg + (int)threadIdx.x;                           \
  if (t < abeg) ACC1(packed[t]);                            \
  int i = abeg + (int)threadIdx.x * 8;                      \
  for (; i + 7 < end; i += BTL * 8) {                       \
    uint4 pa = *(const uint4*)(packed + i);                 \
    uint4 pb = *(const uint4*)(packed + i + 4);             \
    GATH1(m0, pa.x) GATH1(m1, pa.y)                         \
    GATH1(m2, pa.z) GATH1(m3, pa.w)                         \
    GATH1(m4, pb.x) GATH1(m5, pb.y)                         \
    GATH1(m6, pb.z) GATH1(m7, pb.w)                         \
    ATOM1(m0, pa.x) ATOM1(m1, pa.y)                         \
    ATOM1(m2, pa.z) ATOM1(m3, pa.w)                         \
    ATOM1(m4, pb.x) ATOM1(m5, pb.y)                         \
    ATOM1(m6, pb.z) ATOM1(m7, pb.w)                         \
  }                                                         \
  for (; i < end; ++i) ACC1(packed[i]);

// Layer 1 (1->3)
__global__ __launch_bounds__(BTL, 8) void k_layer1(
    const int* __restrict__ scanT, const unsigned int* __restrict__ packed,
    const float* __restrict__ sIn, const float* __restrict__ norm,
    const float* __restrict__ W1, const float* __restrict__ b1,
    float* __restrict__ sNext, int N) {
  __shared__ float a[BSIZE];
  int k = blockIdx.x;
  for (int ii = threadIdx.x; ii < BSIZE; ii += BTL) a[ii] = 0.0f;
  int beg = scanT[k << 2], end = scanT[(k << 2) + 4];
  __syncthreads();
  EDGE_LOOP1
  __syncthreads();
  int node0 = k << BSHIFT;
  for (int tt = threadIdx.x; tt < BSIZE; tt += BTL) {
    int node = node0 + tt;
    if (node >= N) break;
    float n = norm[node];
    float pre = a[tt] * n;
    float h0 = fmaxf(0.0f, pre * W1[0] + b1[0]);
    float h1 = fmaxf(0.0f, pre * W1[1] + b1[1]);
    float h2 = fmaxf(0.0f, pre * W1[2] + b1[2]);
    ((float4*)sNext)[node] = make_float4(h0 * n, h1 * n, h2 * n, 0.0f);
  }
}

// Layers 2-4 (3->3)
__global__ __launch_bounds__(BTL, 8) void k_layer3(
    const int* __restrict__ scanT, const unsigned int* __restrict__ packed,
    const float* __restrict__ sPrev, const float* __restrict__ norm,
    const float* __restrict__ W, const float* __restrict__ bias,
    float* __restrict__ sNext, int N) {
  __shared__ float a0[BSIZE], a1[BSIZE], a2[BSIZE];
  int k = blockIdx.x;
  for (int ii = threadIdx.x; ii < BSIZE; ii += BTL) { a0[ii] = 0.0f; a1[ii] = 0.0f; a2[ii] = 0.0f; }
  int beg = scanT[k << 2], end = scanT[(k << 2) + 4];
  __syncthreads();
  EDGE_LOOP3
  __syncthreads();
  int node0 = k << BSHIFT;
  for (int tt = threadIdx.x; tt < BSIZE; tt += BTL) {
    int node = node0 + tt;
    if (node >= N) break;
    float n = norm[node];
    float x0 = a0[tt] * n, x1 = a1[tt] * n, x2 = a2[tt] * n;
    float h0 = fmaxf(0.0f, x0 * W[0] + x1 * W[3] + x2 * W[6] + bias[0]);
    float h1 = fmaxf(0.0f, x0 * W[1] + x1 * W[4] + x2 * W[7] + bias[1]);
    float h2 = fmaxf(0.0f, x0 * W[2] + x1 * W[5] + x2 * W[8] + bias[2]);
    ((float4*)sNext)[node] = make_float4(h0 * n, h1 * n, h2 * n, 0.0f);
  }
}

// Layer 5 (3->3) + layer-6 pre-transform: sB = (relu(agg*n @ W5 + b5) @ W6) * n
__global__ __launch_bounds__(BTL, 8) void k_layer5(
    const int* __restrict__ scanT, const unsigned int* __restrict__ packed,
    const float* __restrict__ sPrev, const float* __restrict__ norm,
    const float* __restrict__ W5, const float* __restrict__ b5,
    const float* __restrict__ W6, float* __restrict__ sB, int N) {
  __shared__ float a0[BSIZE], a1[BSIZE], a2[BSIZE];
  int k = blockIdx.x;
  for (int ii = threadIdx.x; ii < BSIZE; ii += BTL) { a0[ii] = 0.0f; a1[ii] = 0.0f; a2[ii] = 0.0f; }
  int beg = scanT[k << 2], end = scanT[(k << 2) + 4];
  __syncthreads();
  EDGE_LOOP3
  __syncthreads();
  int node0 = k << BSHIFT;
  for (int tt = threadIdx.x; tt < BSIZE; tt += BTL) {
    int node = node0 + tt;
    if (node >= N) break;
    float n = norm[node];
    float x0 = a0[tt] * n, x1 = a1[tt] * n, x2 = a2[tt] * n;
    float h0 = fmaxf(0.0f, x0 * W5[0] + x1 * W5[3] + x2 * W5[6] + b5[0]);
    float h1 = fmaxf(0.0f, x0 * W5[1] + x1 * W5[4] + x2 * W5[7] + b5[1]);
    float h2 = fmaxf(0.0f, x0 * W5[2] + x1 * W5[5] + x2 * W5[8] + b5[2]);
    sB[node] = (h0 * W6[0] + h1 * W6[1] + h2 * W6[2]) * n;
  }
}

// Layer 6 (scalar): out = relu(agg * n + b6)
__global__ __launch_bounds__(BTL, 8) void k_layer6(
    const int* __restrict__ scanT, const unsigned int* __restrict__ packed,
    const float* __restrict__ sIn, const float* __restrict__ norm,
    const float* __restrict__ b6, float* __restrict__ out, int N) {
  __shared__ float a[BSIZE];
  int k = blockIdx.x;
  for (int ii = threadIdx.x; ii < BSIZE; ii += BTL) a[ii] = 0.0f;
  int beg = scanT[k << 2], end = scanT[(k << 2) + 4];
  __syncthreads();
  EDGE_LOOP1
  __syncthreads();
  int node0 = k << BSHIFT;
  for (int tt = threadIdx.x; tt < BSIZE; tt += BTL) {
    int node = node0 + tt;
    if (node >= N) break;
    out[node] = fmaxf(0.0f, a[tt] * norm[node] + b6[0]);
  }
}

extern "C" void kernel_launch(void* const* d_in, const int* in_sizes, int n_in,
                              void* d_out, int out_size, void* d_ws, size_t ws_size,
                              hipStream_t stream) {
  const float* feat = (const float*)d_in[0];
  const float* norm = (const float*)d_in[1];
  const int* src = (const int*)d_in[2];
  const int* dst = (const int*)d_in[3];
  const float* W1 = (const float*)d_in[4];
  const float* b1 = (const float*)d_in[5];
  const float* W2 = (const float*)d_in[6];
  const float* b2 = (const float*)d_in[7];
  const float* W3 = (const float*)d_in[8];
  const float* b3 = (const float*)d_in[9];
  const float* W4 = (const float*)d_in[10];
  const float* b4 = (const float*)d_in[11];
  const float* W5 = (const float*)d_in[12];
  const float* b5 = (const float*)d_in[13];
  const float* W6 = (const float*)d_in[14];
  const float* b6 = (const float*)d_in[15];
  float* out = (float*)d_out;

  const int N = in_sizes[0];
  const int E = in_sizes[2];
  const int nbNode = (N + BT - 1) / BT;
  const int nBkt = (N + BSIZE - 1) >> BSHIFT;                 // 489
  const int chunk = (((E + NBLK - 1) / NBLK) + 3) & ~3;       // 16B-aligned chunks

  // Workspace: packed[E] | scanT[M] | partial[M/BT] | s0B[N]f | sA[4N]f |
  //            sA2[4N]f (~102 MB). histB/histT (2MB+2MB) alias sA: they are
  //            dead before k_layer1 first writes sA.
  unsigned int* packed = (unsigned int*)d_ws;
  int* scanT = (int*)(packed + (size_t)E);
  int* partial = scanT + (size_t)M;
  float* s0B = (float*)(partial + M / BT);
  float* sA = s0B + (size_t)N;
  float* sA2 = sA + (size_t)4 * N;
  int* histB = (int*)sA;            // build-phase only
  int* histT = histB + (size_t)M;   // build-phase only

  // --- Build (dst_bucket, src_superblock)-ordered edge list ---
  k_init<<<nbNode, BT, 0, stream>>>(feat, norm, s0B, N);
  k_phist<<<NBLK, BT, 0, stream>>>(src, dst, histB, E, chunk);
  {
    dim3 g1(NBINS / 64, NBLK / 64);  // histB[NBLK][NBINS] -> histT[NBINS][NBLK]
    k_transp<<<g1, BT, 0, stream>>>(histB, histT, NBLK, NBINS);
  }
  k_blockSum<<<M / BT, BT, 0, stream>>>(histT, partial, M);
  k_scanPartials<<<1, BT, 0, stream>>>(partial, M / BT);
  k_scanFinal<<<M / BT, BT, 0, stream>>>(histT, partial, M);
  {
    dim3 g2(NBLK / 64, NBINS / 64);  // histT[NBINS][NBLK] (scanned) -> scanT[NBLK][NBINS]
    k_transp<<<g2, BT, 0, stream>>>(histT, scanT, NBINS, NBLK);
  }
  k_pscatter<<<NBLK, BT, 0, stream>>>(src, dst, scanT, packed, E, chunk);

  // --- 6 fused layers ---
  k_layer1<<<nBkt, BTL, 0, stream>>>(scanT, packed, s0B, norm, W1, b1, sA, N);
  k_layer3<<<nBkt, BTL, 0, stream>>>(scanT, packed, sA, norm, W2, b2, sA2, N);
  k_layer3<<<nBkt, BTL, 0, stream>>>(scanT, packed, sA2, norm, W3, b3, sA, N);
  k_layer3<<<nBkt, BTL, 0, stream>>>(scanT, packed, sA, norm, W4, b4, sA2, N);
  k_layer5<<<nBkt, BTL, 0, stream>>>(scanT, packed, sA2, norm, W5, b5, W6, s0B, N);
  k_layer6<<<nBkt, BTL, 0, stream>>>(scanT, packed, s0B, norm, b6, out, N);
}